// Round 5
// baseline (1363.227 us; speedup 1.0000x reference)
//
#include <hip/hip_runtime.h>
#include <math.h>

typedef _Float16 f16x8 __attribute__((ext_vector_type(8)));
typedef float    f32x4 __attribute__((ext_vector_type(4)));

namespace {
constexpr int SEQ   = 512;
constexpr int VOCAB = 128;
constexpr int EMBED = 128;
constexpr int HID   = 256;
constexpr int NSTEP = 511;
constexpr int BLK   = 256;    // 4 waves
constexpr int NROW  = 16;     // batch rows per block == MFMA M
constexpr int NBLK  = 32;     // 512/16
constexpr int NTA   = 4;      // 16-wide j-tiles per wave   (4 waves x 4 = HID/16)
constexpr int NTB   = 2;      // 16-wide v-tiles per wave   (4 waves x 2 = VOCAB/16)
}

// P[v][j] = dot(emb[v,:], Wxh[j,:]) — folds the Wxh matmul into a row gather.
// Validated in round 3 (passed).
__device__ float g_P[VOCAB * HID];

__global__ void precompute_P(const float* __restrict__ emb,
                             const float* __restrict__ Wxh)
{
    __shared__ __align__(16) float es[EMBED];
    const int v = blockIdx.x;
    const int j = threadIdx.x;
    if (j < EMBED) es[j] = emb[(size_t)v * EMBED + j];
    __syncthreads();
    const float4* w4 = (const float4*)(Wxh + (size_t)j * EMBED);
    const float4* e4 = (const float4*)es;
    float a = 0.f;
    #pragma unroll
    for (int k = 0; k < EMBED / 4; ++k) {
        float4 w = w4[k], e = e4[k];
        a += w.x * e.x + w.y * e.y + w.z * e.z + w.w * e.w;
    }
    g_P[v * HID + j] = a;
}

// load 8 fp32 -> (hi, lo) f16 fragments;  hi+lo reproduces fp32 to ~2^-22.
__device__ __forceinline__ void load_hilo(const float* s, f16x8& h8, f16x8& l8)
{
    float4 A = *(const float4*)s, B = *(const float4*)(s + 4);
    _Float16 h;
    h = (_Float16)A.x; h8[0] = h; l8[0] = (_Float16)(A.x - (float)h);
    h = (_Float16)A.y; h8[1] = h; l8[1] = (_Float16)(A.y - (float)h);
    h = (_Float16)A.z; h8[2] = h; l8[2] = (_Float16)(A.z - (float)h);
    h = (_Float16)A.w; h8[3] = h; l8[3] = (_Float16)(A.w - (float)h);
    h = (_Float16)B.x; h8[4] = h; l8[4] = (_Float16)(B.x - (float)h);
    h = (_Float16)B.y; h8[5] = h; l8[5] = (_Float16)(B.y - (float)h);
    h = (_Float16)B.z; h8[6] = h; l8[6] = (_Float16)(B.z - (float)h);
    h = (_Float16)B.w; h8[7] = h; l8[7] = (_Float16)(B.w - (float)h);
}

// LDS h layout (per buffer, per hi/lo array): row-major [m=16][k=256] f16,
// byte(m,k) = 512*m + 16*((k>>3) ^ (m&7)) + 2*(k&7).
// A-frag ds_read_b128 (granule 4f+lh, rows m=ll): 8 phys slots x 2 lanes = 2-way (free).

__global__ __launch_bounds__(BLK, 1)
void rnn_mfma5(const int* __restrict__ x,   const float* __restrict__ Whh,
               const float* __restrict__ bhh, const float* __restrict__ bxh,
               const float* __restrict__ Why, const float* __restrict__ bhy,
               const float* __restrict__ h0,  float* __restrict__ out)
{
    __shared__ __align__(16) _Float16 hbuf_hi[2][NROW][HID];   // 16 KB
    __shared__ __align__(16) _Float16 hbuf_lo[2][NROW][HID];   // 16 KB

    const int tid  = threadIdx.x;
    const int w    = tid >> 6;        // wave 0..3
    const int lane = tid & 63;
    const int ll   = lane & 15;       // MFMA A-row m / C-col n
    const int lh   = lane >> 4;       // 0..3
    const int r0   = blockIdx.x * NROW;

    // ---- persistent weight fragments ----
    // element e of frag f: k = 32f + 8*lh + e  (same map as the LDS A-frag read)
    f16x8 wa_hi[NTA][8], wa_lo[NTA][8];   // Whh rows j = 64w + 16a + ll
    #pragma unroll
    for (int a = 0; a < NTA; ++a)
        #pragma unroll
        for (int f = 0; f < 8; ++f)
            load_hilo(Whh + (size_t)(64 * w + 16 * a + ll) * HID + 32 * f + 8 * lh,
                      wa_hi[a][f], wa_lo[a][f]);
    f16x8 wy_hi[NTB][8];                  // Why rows v = 32w + 16b + ll (hi only)
    #pragma unroll
    for (int b = 0; b < NTB; ++b)
        #pragma unroll
        for (int f = 0; f < 8; ++f) {
            f16x8 dummy_lo;
            load_hilo(Why + (size_t)(32 * w + 16 * b + ll) * HID + 32 * f + 8 * lh,
                      wy_hi[b][f], dummy_lo);
        }

    // ---- stage h(0) = h0 broadcast to all 16 rows, into buf[1] ----
    {
        int k = tid;                  // 0..255
        float v = h0[k];
        _Float16 hi = (_Float16)v;
        _Float16 lo = (_Float16)(v - (float)hi);
        int g = k >> 3, bb = k & 7;
        #pragma unroll
        for (int m = 0; m < NROW; ++m) {
            int e = ((g ^ (m & 7)) << 3) + bb;      // f16 element within row
            hbuf_hi[1][m][e] = hi;
            hbuf_lo[1][m][e] = lo;
        }
    }

    // ---- x-path: u_x(t) = P[idx_t] + P[idx_0];  biases folded into cst ----
    float cst[NTA][4], pt[NTA][4];
    int   inx[4];
    #pragma unroll
    for (int r = 0; r < 4; ++r) {
        const size_t xrow = (size_t)(r0 + 4 * lh + r) * SEQ;
        int i0 = x[xrow];
        #pragma unroll
        for (int a = 0; a < NTA; ++a) {
            int j = 64 * w + 16 * a + ll;
            float p = g_P[(size_t)i0 * HID + j];
            pt[a][r]  = p;                           // P[idx_t], t=0
            cst[a][r] = p + bhh[j] + bxh[j];         // P[idx_0] + b (invariant)
        }
        inx[r] = x[xrow + 1];                        // idx for t+1
    }
    float bv[NTB];
    #pragma unroll
    for (int b = 0; b < NTB; ++b) bv[b] = bhy[32 * w + 16 * b + ll];

    // loop-invariant A-frag byte offsets (within a buffer)
    int aoff[8];
    #pragma unroll
    for (int f = 0; f < 8; ++f)
        aoff[f] = 512 * ll + ((((f << 2) + lh) ^ (ll & 7)) << 4);

    __syncthreads();

    // A-frags of h(0) from buf[1]
    f16x8 af_hi[8], af_lo[8];
    #pragma unroll
    for (int f = 0; f < 8; ++f) {
        af_hi[f] = *(const f16x8*)((const char*)&hbuf_hi[1][0][0] + aoff[f]);
        af_lo[f] = *(const f16x8*)((const char*)&hbuf_lo[1][0][0] + aoff[f]);
    }

    for (int t = 0; t < NSTEP; ++t) {
        // ===== phase A: u = Whh*h  (hi*hi + lo*hi + hi*lo), 4 j-tiles =====
        f32x4 acc_hh[NTA] = {{0,0,0,0},{0,0,0,0},{0,0,0,0},{0,0,0,0}};
        f32x4 acc_cr[NTA] = {{0,0,0,0},{0,0,0,0},{0,0,0,0},{0,0,0,0}};
        #pragma unroll
        for (int f = 0; f < 8; ++f) {
            #pragma unroll
            for (int a = 0; a < NTA; ++a)
                acc_hh[a] = __builtin_amdgcn_mfma_f32_16x16x32_f16(af_hi[f], wa_hi[a][f], acc_hh[a], 0, 0, 0);
            #pragma unroll
            for (int a = 0; a < NTA; ++a)
                acc_cr[a] = __builtin_amdgcn_mfma_f32_16x16x32_f16(af_lo[f], wa_hi[a][f], acc_cr[a], 0, 0, 0);
            #pragma unroll
            for (int a = 0; a < NTA; ++a)
                acc_cr[a] = __builtin_amdgcn_mfma_f32_16x16x32_f16(af_hi[f], wa_lo[a][f], acc_cr[a], 0, 0, 0);
        }

        // ===== tanh + split + store h(t+1) into buf[t&1] =====
        char* whi = (char*)&hbuf_hi[t & 1][0][0];
        char* wlo = (char*)&hbuf_lo[t & 1][0][0];
        #pragma unroll
        for (int a = 0; a < NTA; ++a) {
            #pragma unroll
            for (int r = 0; r < 4; ++r) {
                float u = (acc_hh[a][r] + acc_cr[a][r]) + cst[a][r] + pt[a][r];
                float e  = __expf(2.0f * u);                 // tanh, inf-safe
                float hv = 1.0f - 2.0f / (e + 1.0f);
                _Float16 hi = (_Float16)hv;
                _Float16 lo = (_Float16)(hv - (float)hi);
                int m = 4 * lh + r;
                int j = 64 * w + 16 * a + ll;
                int off = 512 * m + ((((j >> 3)) ^ (m & 7)) << 4) + ((j & 7) << 1);
                *(_Float16*)(whi + off) = hi;
                *(_Float16*)(wlo + off) = lo;
            }
        }

        // reload pt (P rows for t+1; consumed next step) and idx for t+2
        #pragma unroll
        for (int r = 0; r < 4; ++r)
            #pragma unroll
            for (int a = 0; a < NTA; ++a)
                pt[a][r] = g_P[(size_t)inx[r] * HID + 64 * w + 16 * a + ll];
        {
            int tt = (t + 2 < SEQ) ? t + 2 : SEQ - 1;
            #pragma unroll
            for (int r = 0; r < 4; ++r)
                inx[r] = x[(size_t)(r0 + 4 * lh + r) * SEQ + tt];
        }

        __syncthreads();   // sole barrier: h(t+1) visible

        // ===== re-read A-frags (h(t+1)) — feeds phase B now and phase A next =====
        const char* rhi = (const char*)&hbuf_hi[t & 1][0][0];
        const char* rlo = (const char*)&hbuf_lo[t & 1][0][0];
        #pragma unroll
        for (int f = 0; f < 8; ++f) {
            af_hi[f] = *(const f16x8*)(rhi + aoff[f]);
            af_lo[f] = *(const f16x8*)(rlo + aoff[f]);
        }

        // ===== phase B: y_t = h(t+1) * Why^T + bhy  (2 v-tiles, hi path) =====
        f32x4 yb[NTB] = {{0,0,0,0},{0,0,0,0}};
        #pragma unroll
        for (int f = 0; f < 8; ++f)
            #pragma unroll
            for (int b = 0; b < NTB; ++b)
                yb[b] = __builtin_amdgcn_mfma_f32_16x16x32_f16(af_hi[f], wy_hi[b][f], yb[b], 0, 0, 0);
        #pragma unroll
        for (int b = 0; b < NTB; ++b)
            #pragma unroll
            for (int r = 0; r < 4; ++r)
                out[((size_t)(r0 + 4 * lh + r) * NSTEP + t) * VOCAB + 32 * w + 16 * b + ll]
                    = yb[b][r] + bv[b];
    }
}

extern "C" void kernel_launch(void* const* d_in, const int* in_sizes, int n_in,
                              void* d_out, int out_size, void* d_ws, size_t ws_size,
                              hipStream_t stream)
{
    (void)in_sizes; (void)n_in; (void)d_ws; (void)ws_size; (void)out_size;
    const int*   x   = (const int*)  d_in[0];
    const float* emb = (const float*)d_in[1];
    const float* Whh = (const float*)d_in[2];
    const float* bhh = (const float*)d_in[3];
    const float* Wxh = (const float*)d_in[4];
    const float* bxh = (const float*)d_in[5];
    const float* Why = (const float*)d_in[6];
    const float* bhy = (const float*)d_in[7];
    const float* h0  = (const float*)d_in[8];
    float* out = (float*)d_out;

    precompute_P<<<VOCAB, 256, 0, stream>>>(emb, Wxh);
    rnn_mfma5<<<NBLK, BLK, 0, stream>>>(x, Whh, bhh, bxh, Why, bhy, h0, out);
}

// Round 7
// 1146.074 us; speedup vs baseline: 1.1895x; 1.1895x over previous
//
#include <hip/hip_runtime.h>
#include <math.h>

typedef _Float16 f16x8 __attribute__((ext_vector_type(8)));
typedef float    f32x4 __attribute__((ext_vector_type(4)));

namespace {
constexpr int SEQ   = 512;
constexpr int VOCAB = 128;
constexpr int EMBED = 128;
constexpr int HID   = 256;
constexpr int NSTEP = 511;
constexpr int BLK   = 512;    // 8 waves -> 2 waves/SIMD
constexpr int NROW  = 16;     // batch rows per block == MFMA M
constexpr int NBLK  = 32;     // 512/16
constexpr int NTA   = 2;      // j-tiles per wave (8 waves x 2 x 16 = HID)
}

// P[v][j] = dot(emb[v,:], Wxh[j,:]) — folds the Wxh matmul into a row gather.
__device__ float g_P[VOCAB * HID];

__global__ void precompute_P(const float* __restrict__ emb,
                             const float* __restrict__ Wxh)
{
    __shared__ __align__(16) float es[EMBED];
    const int v = blockIdx.x;
    const int j = threadIdx.x;
    if (j < EMBED) es[j] = emb[(size_t)v * EMBED + j];
    __syncthreads();
    const float4* w4 = (const float4*)(Wxh + (size_t)j * EMBED);
    const float4* e4 = (const float4*)es;
    float a = 0.f;
    #pragma unroll
    for (int k = 0; k < EMBED / 4; ++k) {
        float4 w = w4[k], e = e4[k];
        a += w.x * e.x + w.y * e.y + w.z * e.z + w.w * e.w;
    }
    g_P[v * HID + j] = a;
}

// split 8 fp32 -> (hi, lo) f16 fragments; hi+lo reproduces fp32 to ~2^-22.
__device__ __forceinline__ void load_hilo(const float* s, f16x8& h8, f16x8& l8)
{
    float4 A = *(const float4*)s, B = *(const float4*)(s + 4);
    _Float16 h;
    h = (_Float16)A.x; h8[0] = h; l8[0] = (_Float16)(A.x - (float)h);
    h = (_Float16)A.y; h8[1] = h; l8[1] = (_Float16)(A.y - (float)h);
    h = (_Float16)A.z; h8[2] = h; l8[2] = (_Float16)(A.z - (float)h);
    h = (_Float16)A.w; h8[3] = h; l8[3] = (_Float16)(A.w - (float)h);
    h = (_Float16)B.x; h8[4] = h; l8[4] = (_Float16)(B.x - (float)h);
    h = (_Float16)B.y; h8[5] = h; l8[5] = (_Float16)(B.y - (float)h);
    h = (_Float16)B.z; h8[6] = h; l8[6] = (_Float16)(B.z - (float)h);
    h = (_Float16)B.w; h8[7] = h; l8[7] = (_Float16)(B.w - (float)h);
}

// LDS h layout (per buffer, per array): row-major [m=16][k=256] f16,
// byte(m,k) = 512*m + 16*((k>>3) ^ (m&7)) + 2*(k&7).  A-frag b128 reads: uniform
// 8 lanes/bank-group -> conflict-free.

__global__ __launch_bounds__(BLK, 2)
void rnn_mfma6(const int* __restrict__ x,   const float* __restrict__ Whh,
               const float* __restrict__ bhh, const float* __restrict__ bxh,
               const float* __restrict__ Why, const float* __restrict__ bhy,
               const float* __restrict__ h0,  float* __restrict__ out)
{
    __shared__ __align__(16) _Float16 hbuf_hi[2][NROW][HID];   // 16 KB
    __shared__ __align__(16) _Float16 hbuf_lo[2][NROW][HID];   // 16 KB

    const int tid  = threadIdx.x;
    const int w    = tid >> 6;        // wave 0..7
    const int lane = tid & 63;
    const int ll   = lane & 15;       // MFMA A-row m / C-col n
    const int lh   = lane >> 4;       // 0..3
    const int r0   = blockIdx.x * NROW;

    // ---- persistent weight fragments (element e of frag f: k = 32f + 8lh + e) ----
    f16x8 wa_hi[NTA][8], wa_lo[NTA][8];     // Whh rows j = 32w + 16a + ll
    #pragma unroll
    for (int a = 0; a < NTA; ++a)
        #pragma unroll
        for (int f = 0; f < 8; ++f)
            load_hilo(Whh + (size_t)(32 * w + 16 * a + ll) * HID + 32 * f + 8 * lh,
                      wa_hi[a][f], wa_lo[a][f]);
    f16x8 wy[8];                            // Why row v = 16w + ll (hi only)
    #pragma unroll
    for (int f = 0; f < 8; ++f) {
        f16x8 dlo;
        load_hilo(Why + (size_t)(16 * w + ll) * HID + 32 * f + 8 * lh, wy[f], dlo);
    }

    // ---- stage h(0) (broadcast to 16 rows) into buf[0] ----
    {
        int k = tid & 255, half = tid >> 8;          // threads split rows 0-7 / 8-15
        float v = h0[k];
        _Float16 hi = (_Float16)v, lo = (_Float16)(v - (float)hi);
        int g = k >> 3, bb = k & 7;
        #pragma unroll
        for (int mm = 0; mm < 8; ++mm) {
            int m = half * 8 + mm;
            int e = ((g ^ (m & 7)) << 3) + bb;
            hbuf_hi[0][m][e] = hi;
            hbuf_lo[0][m][e] = lo;
        }
    }

    // ---- x-path: u_x(t) = P[idx_t] + P[idx_0]; bias folded ----
    float cst[NTA][4], pt[NTA][4];
    int   inx[4];
    #pragma unroll
    for (int r = 0; r < 4; ++r) {
        const size_t xrow = (size_t)(r0 + 4 * lh + r) * SEQ;
        int i0 = x[xrow];
        #pragma unroll
        for (int a = 0; a < NTA; ++a) {
            int j = 32 * w + 16 * a + ll;
            float p = g_P[(size_t)i0 * HID + j];
            pt[a][r]  = p;
            cst[a][r] = p + bhh[j] + bxh[j];
        }
        inx[r] = x[xrow + 1];
    }
    const float bv = bhy[16 * w + ll];

    // loop-invariant A-frag read offsets
    int aoff[8];
    #pragma unroll
    for (int f = 0; f < 8; ++f)
        aoff[f] = 512 * ll + ((((f << 2) + lh) ^ (ll & 7)) << 4);

    float* outp = out + (size_t)(r0 + 4 * lh) * NSTEP * VOCAB + 16 * w + ll; // t=0 pos

    __syncthreads();

    for (int i = 0; i < SEQ; ++i) {              // iter i: A: h(i)->h(i+1); B: y(i-1)
        // ---- P rows for next tanh + idx for i+2, issued first (covered by MFMAs) ----
        float pn[NTA][4];
        #pragma unroll
        for (int r = 0; r < 4; ++r)
            #pragma unroll
            for (int a = 0; a < NTA; ++a)
                pn[a][r] = g_P[(size_t)inx[r] * HID + 32 * w + 16 * a + ll];
        {
            int tt = (i + 2 < SEQ) ? i + 2 : SEQ - 1;
            #pragma unroll
            for (int r = 0; r < 4; ++r)
                inx[r] = x[(size_t)(r0 + 4 * lh + r) * SEQ + tt];
        }

        // ---- fused read + MFMA: yb (phase B of y(i-1)) + phase A of h(i+1) ----
        const char* rhi = (const char*)&hbuf_hi[i & 1][0][0];
        const char* rlo = (const char*)&hbuf_lo[i & 1][0][0];
        f32x4 yb = {bv, bv, bv, bv};
        f32x4 ah[NTA], ac[NTA];
        #pragma unroll
        for (int a = 0; a < NTA; ++a) {
            f32x4 c0 = {cst[a][0] + pt[a][0], cst[a][1] + pt[a][1],
                        cst[a][2] + pt[a][2], cst[a][3] + pt[a][3]};
            ah[a] = c0;
            ac[a] = (f32x4){0.f, 0.f, 0.f, 0.f};
        }
        #pragma unroll
        for (int f = 0; f < 8; ++f) {
            f16x8 fh = *(const f16x8*)(rhi + aoff[f]);
            f16x8 fl = *(const f16x8*)(rlo + aoff[f]);
            yb = __builtin_amdgcn_mfma_f32_16x16x32_f16(fh, wy[f], yb, 0, 0, 0);
            #pragma unroll
            for (int a = 0; a < NTA; ++a)
                ah[a] = __builtin_amdgcn_mfma_f32_16x16x32_f16(fh, wa_hi[a][f], ah[a], 0, 0, 0);
            #pragma unroll
            for (int a = 0; a < NTA; ++a)
                ac[a] = __builtin_amdgcn_mfma_f32_16x16x32_f16(fl, wa_hi[a][f], ac[a], 0, 0, 0);
            #pragma unroll
            for (int a = 0; a < NTA; ++a)
                ac[a] = __builtin_amdgcn_mfma_f32_16x16x32_f16(fh, wa_lo[a][f], ac[a], 0, 0, 0);
        }

        // ---- store y(i-1) ----
        if (i > 0) {
            #pragma unroll
            for (int r = 0; r < 4; ++r)
                outp[(size_t)r * NSTEP * VOCAB] = yb[r];
            outp += VOCAB;
        }

        // ---- tanh + hi/lo split + store h(i+1) into buf[(i+1)&1] ----
        if (i < NSTEP) {
            char* whi_ = (char*)&hbuf_hi[(i + 1) & 1][0][0];
            char* wlo_ = (char*)&hbuf_lo[(i + 1) & 1][0][0];
            #pragma unroll
            for (int a = 0; a < NTA; ++a) {
                #pragma unroll
                for (int r = 0; r < 4; ++r) {
                    float u  = ah[a][r] + ac[a][r];
                    float e  = __expf(2.0f * u);
                    float hv = 1.0f - 2.0f / (e + 1.0f);          // tanh, inf-safe
                    _Float16 hi = (_Float16)hv;
                    _Float16 lo = (_Float16)(hv - (float)hi);
                    int m = 4 * lh + r;
                    int j = 32 * w + 16 * a + ll;
                    int off = 512 * m + ((((j >> 3)) ^ (m & 7)) << 4) + ((j & 7) << 1);
                    *(_Float16*)(whi_ + off) = hi;
                    *(_Float16*)(wlo_ + off) = lo;
                    pt[a][r] = pn[a][r];
                }
            }
        }

        __syncthreads();
    }
}

extern "C" void kernel_launch(void* const* d_in, const int* in_sizes, int n_in,
                              void* d_out, int out_size, void* d_ws, size_t ws_size,
                              hipStream_t stream)
{
    (void)in_sizes; (void)n_in; (void)d_ws; (void)ws_size; (void)out_size;
    const int*   x   = (const int*)  d_in[0];
    const float* emb = (const float*)d_in[1];
    const float* Whh = (const float*)d_in[2];
    const float* bhh = (const float*)d_in[3];
    const float* Wxh = (const float*)d_in[4];
    const float* bxh = (const float*)d_in[5];
    const float* Why = (const float*)d_in[6];
    const float* bhy = (const float*)d_in[7];
    const float* h0  = (const float*)d_in[8];
    float* out = (float*)d_out;

    precompute_P<<<VOCAB, 256, 0, stream>>>(emb, Wxh);
    rnn_mfma6<<<NBLK, BLK, 0, stream>>>(x, Whh, bhh, bxh, Why, bhy, h0, out);
}